// Round 5
// baseline (95.940 us; speedup 1.0000x reference)
//
#include <hip/hip_runtime.h>
#include <hip/hip_bf16.h>
#include <cstdint>
#include <cstddef>

#define B_ROWS 8192
#define KDIM   4096
#define IN_DIM 2048
#define HIDDEN 2048
#define NJ     32             // 4 gates x 8 wires
#define WAVES  8              // waves per block; wave w owns k-chunk w*512
#define TPB    (WAVES * 64)   // 512 threads
#define CHUNK  (KDIM / WAVES) // 512
#define KSTEPS (CHUNK / 32)   // 16 MFMA K-steps per wave

typedef __bf16 bf16x8 __attribute__((ext_vector_type(8)));
typedef float  f32x4  __attribute__((ext_vector_type(4)));

__device__ __forceinline__ bf16x8 cvt8(f32x4 a, f32x4 b) {
    bf16x8 r;
    r[0] = (__bf16)a.x; r[1] = (__bf16)a.y; r[2] = (__bf16)a.z; r[3] = (__bf16)a.w;
    r[4] = (__bf16)b.x; r[5] = (__bf16)b.y; r[6] = (__bf16)b.z; r[7] = (__bf16)b.w;
    return r;
}

// ---------- Fused GEMM + cos + reduce: one block = 16 rows x full K ----------
// grid = 512 blocks * 512 thr (8 waves). Wave w: k in [w*512, w*512+512).
// Partial 16x32 tiles meet in LDS; block reduces, cos, 4 atomicAdds to q[4].
extern "C" __global__ __launch_bounds__(TPB, 4)
void p12_fused(const float* __restrict__ x,  const float* __restrict__ hx,
               const float* __restrict__ Wf, const float* __restrict__ Wi,
               const float* __restrict__ Wg, const float* __restrict__ Wo,
               const float* __restrict__ bf, const float* __restrict__ bi,
               const float* __restrict__ bg, const float* __restrict__ bo,
               float* __restrict__ q)
{
    __shared__ float Sp[WAVES][16][NJ];   // 16 KB partial tiles
    __shared__ float ql[4];

    const int tid  = threadIdx.x;
    if (tid < 4) ql[tid] = 0.f;

    const int wave = tid >> 6;
    const int lane = tid & 63;
    const int lrow = lane & 15;            // A row / B col within fragment
    const int koff = (lane >> 4) * 8;      // 8 consecutive k per lane
    const int row0 = blockIdx.x * 16;
    const int k0   = wave * CHUNK;

    // A: waves 0-3 stream x, waves 4-7 stream hx (chunk never straddles)
    const float* Abase = (wave < 4)
        ? (x  + (size_t)(row0 + lrow) * IN_DIM + k0 + koff)
        : (hx + (size_t)(row0 + lrow) * HIDDEN + (k0 - IN_DIM) + koff);
    // B cols: acc0 -> j = lrow (gates f,i); acc1 -> j = 16+lrow (gates g,o)
    const float* B0 = ((lrow & 8) ? Wi : Wf) + (size_t)(lrow & 7) * KDIM + k0 + koff;
    const float* B1 = ((lrow & 8) ? Wo : Wg) + (size_t)(lrow & 7) * KDIM + k0 + koff;

    f32x4 acc0 = {0.f, 0.f, 0.f, 0.f};
    f32x4 acc1 = {0.f, 0.f, 0.f, 0.f};

#pragma unroll 4
    for (int s = 0; s < KSTEPS; ++s) {
        const float* ap = Abase + s * 32;
        // A streams once from HBM: non-temporal
        f32x4 a0 = __builtin_nontemporal_load(reinterpret_cast<const f32x4*>(ap));
        f32x4 a1 = __builtin_nontemporal_load(reinterpret_cast<const f32x4*>(ap) + 1);
        // W is tiny (512 KB) and reused by all blocks: normal cached loads (L2)
        f32x4 w00 = *(reinterpret_cast<const f32x4*>(B0 + s * 32));
        f32x4 w01 = *(reinterpret_cast<const f32x4*>(B0 + s * 32) + 1);
        f32x4 w10 = *(reinterpret_cast<const f32x4*>(B1 + s * 32));
        f32x4 w11 = *(reinterpret_cast<const f32x4*>(B1 + s * 32) + 1);

        bf16x8 af  = cvt8(a0, a1);
        bf16x8 bf0 = cvt8(w00, w01);
        bf16x8 bf1 = cvt8(w10, w11);
        acc0 = __builtin_amdgcn_mfma_f32_16x16x32_bf16(af, bf0, acc0, 0, 0, 0);
        acc1 = __builtin_amdgcn_mfma_f32_16x16x32_bf16(af, bf1, acc1, 0, 0, 0);
    }

    // D layout (16x16x32): col = lane&15, row = (lane>>4)*4 + reg
    const int m0 = (lane >> 4) * 4;
#pragma unroll
    for (int r = 0; r < 4; ++r) {
        Sp[wave][m0 + r][lrow]      = acc0[r];
        Sp[wave][m0 + r][16 + lrow] = acc1[r];
    }
    __syncthreads();

    // 512 threads <-> 512 (row,j) cells: sum 8 wave-partials, bias, cos
    const int m = tid >> 5;          // 0..15
    const int j = tid & 31;          // 0..31
    float ssum = 0.f;
#pragma unroll
    for (int w = 0; w < WAVES; ++w) ssum += Sp[w][m][j];
    const int gate = j >> 3;
    const float* Bp = (gate == 0) ? bf : (gate == 1) ? bi : (gate == 2) ? bg : bo;
    float v = cosf(ssum + Bp[j & 7]);

    // 8-lane group shares one gate
    v += __shfl_xor(v, 1, 64);
    v += __shfl_xor(v, 2, 64);
    v += __shfl_xor(v, 4, 64);
    if ((tid & 7) == 0) atomicAdd(&ql[gate], v);
    __syncthreads();
    if (tid < 4) atomicAdd(&q[tid], ql[tid]);
}

// ---------------- Elementwise LSTM update ----------------
extern "C" __global__ __launch_bounds__(256)
void p3_elementwise(const float* __restrict__ cx, const float* __restrict__ q,
                    float* __restrict__ out)
{
    const float qf = q[0], qi = q[1], qg = q[2], qo = q[3];
    const float f  = 1.f / (1.f + expf(-qf));
    const float ii = 1.f / (1.f + expf(-qi));
    const float g  = tanhf(qg);
    const float o  = 1.f / (1.f + expf(-qo));
    const float ig = ii * g;

    const size_t N  = (size_t)B_ROWS * HIDDEN;     // 16,777,216
    const size_t N4 = N >> 2;
    const f32x4* cx4 = (const f32x4*)cx;
    f32x4* outh = (f32x4*)out;
    f32x4* outc = (f32x4*)(out + N);

    for (size_t idx = (size_t)blockIdx.x * blockDim.x + threadIdx.x; idx < N4;
         idx += (size_t)gridDim.x * blockDim.x) {
        f32x4 c = __builtin_nontemporal_load(cx4 + idx);  // streaming, no reuse
        f32x4 cn, hn;
        cn.x = fmaf(f, c.x, ig);
        cn.y = fmaf(f, c.y, ig);
        cn.z = fmaf(f, c.z, ig);
        cn.w = fmaf(f, c.w, ig);
        hn.x = o * tanhf(cn.x);
        hn.y = o * tanhf(cn.y);
        hn.z = o * tanhf(cn.z);
        hn.w = o * tanhf(cn.w);
        outc[idx] = cn;
        outh[idx] = hn;
    }
}

// ---------------- launcher ----------------
extern "C" void kernel_launch(void* const* d_in, const int* in_sizes, int n_in,
                              void* d_out, int out_size, void* d_ws, size_t ws_size,
                              hipStream_t stream)
{
    const float* x  = (const float*)d_in[0];
    const float* hx = (const float*)d_in[1];
    const float* cx = (const float*)d_in[2];
    const float* Wf = (const float*)d_in[3];
    const float* bf = (const float*)d_in[4];
    const float* Wi = (const float*)d_in[5];
    const float* bi = (const float*)d_in[6];
    const float* Wg = (const float*)d_in[7];
    const float* bg = (const float*)d_in[8];
    const float* Wo = (const float*)d_in[9];
    const float* bo = (const float*)d_in[10];
    float* out = (float*)d_out;

    float* q = (float*)d_ws;   // 4 floats of scratch

    // q accumulates via atomics -> must be zero at the start of every call
    hipMemsetAsync(q, 0, 4 * sizeof(float), stream);

    p12_fused<<<dim3(B_ROWS / 16), dim3(TPB), 0, stream>>>(
        x, hx, Wf, Wi, Wg, Wo, bf, bi, bg, bo, q);
    p3_elementwise<<<dim3(2048), dim3(256), 0, stream>>>(cx, q, out);
}

// Round 6
// 81.308 us; speedup vs baseline: 1.1800x; 1.1800x over previous
//
#include <hip/hip_runtime.h>
#include <hip/hip_bf16.h>
#include <cstdint>
#include <cstddef>

#define B_ROWS 8192
#define KDIM   4096
#define IN_DIM 2048
#define HIDDEN 2048
#define NJ     32           // 4 gates x 8 wires
#define KC     8            // K-split across blocks
#define CHUNK  (KDIM / KC)  // 512
#define BK     64           // k-subtile staged in LDS
#define SUBT   (CHUNK / BK) // 8
#define LDSP   80           // padded LDS row stride in bf16 (64 + 16)

typedef __bf16 bf16x8 __attribute__((ext_vector_type(8)));
typedef __bf16 bf16x4 __attribute__((ext_vector_type(4)));
typedef float  f32x4  __attribute__((ext_vector_type(4)));

// ---------------- Pass 0: pack weights to bf16 [32][4096]; zero q ---------
extern "C" __global__ __launch_bounds__(256)
void w_pack(const float* __restrict__ Wf, const float* __restrict__ Wi,
            const float* __restrict__ Wg, const float* __restrict__ Wo,
            __bf16* __restrict__ Wb, float* __restrict__ q)
{
    if (blockIdx.x == 0 && threadIdx.x < 4) q[threadIdx.x] = 0.f;

    const int t    = blockIdx.x * 256 + threadIdx.x;   // 0 .. 32767
    const int idx4 = t << 2;
    const int j    = idx4 >> 12;
    const int k    = idx4 & (KDIM - 1);
    const float* W = (j < 8) ? Wf : (j < 16) ? Wi : (j < 24) ? Wg : Wo;
    f32x4 v = *reinterpret_cast<const f32x4*>(W + (size_t)(j & 7) * KDIM + k);
    bf16x4 b;
    b[0] = (__bf16)v.x; b[1] = (__bf16)v.y; b[2] = (__bf16)v.z; b[3] = (__bf16)v.w;
    *reinterpret_cast<bf16x4*>(Wb + idx4) = b;
}

// ---------------- Pass 1: split-K MFMA GEMM, LDS-staged A ----------------
// grid = 128 mblocks * 8 kc; block = 256 thr (4 waves). Block = 64 rows x 512 k.
// Spart layout: [KC][B_ROWS][NJ]
extern "C" __global__ __launch_bounds__(256)
void p1_mfma(const float* __restrict__ x, const float* __restrict__ hx,
             const __bf16* __restrict__ Wb, float* __restrict__ Spart)
{
    __shared__ __bf16 At[64 * LDSP];   // 10,240 B, padded rows

    const int bid  = blockIdx.x;
    const int kc   = bid & (KC - 1);
    const int mb   = bid >> 3;                  // 0..127
    const int tid  = threadIdx.x;
    const int wave = tid >> 6;
    const int lane = tid & 63;
    const int lrow = lane & 15;                 // frag row / B col
    const int koff = (lane >> 4) * 8;           // 8 consecutive k per lane
    const int rowblk = mb * 64;
    const int k0   = kc * CHUNK;

    // x and hx have the same row stride (2048); chunk never straddles them
    const float* Asrc = (kc < 4)
        ? (x  + (size_t)rowblk * IN_DIM + k0)
        : (hx + (size_t)rowblk * HIDDEN + (k0 - IN_DIM));
    const __bf16* B0 = Wb + (size_t)lrow * KDIM + k0 + koff;        // j = lrow
    const __bf16* B1 = B0 + (size_t)16 * KDIM;                      // j = lrow+16

    f32x4 acc0 = {0.f, 0.f, 0.f, 0.f};
    f32x4 acc1 = {0.f, 0.f, 0.f, 0.f};

    for (int sub = 0; sub < SUBT; ++sub) {
        const float* tsrc = Asrc + sub * BK;
        __syncthreads();   // previous subtile fully consumed
        // ---- stage 64 rows x 64 k: per wave a contiguous 1 KB span ----
#pragma unroll
        for (int p = 0; p < 4; ++p) {
            const int slot = p * 256 + tid;     // 0..1023
            const int r    = slot >> 4;         // row 0..63
            const int c4   = slot & 15;         // float4 index within row
            f32x4 v = __builtin_nontemporal_load(
                reinterpret_cast<const f32x4*>(tsrc + (size_t)r * 2048) + c4);
            bf16x4 b;
            b[0] = (__bf16)v.x; b[1] = (__bf16)v.y;
            b[2] = (__bf16)v.z; b[3] = (__bf16)v.w;
            *reinterpret_cast<bf16x4*>(At + r * LDSP + c4 * 4) = b;
        }
        __syncthreads();   // tile visible to all waves

        // ---- 2 K-steps of MFMA; A-frag from LDS, B-frag from L2 ----
#pragma unroll
        for (int st = 0; st < 2; ++st) {
            bf16x8 af = *reinterpret_cast<const bf16x8*>(
                At + (wave * 16 + lrow) * LDSP + st * 32 + koff);
            bf16x8 b0 = *reinterpret_cast<const bf16x8*>(B0 + sub * BK + st * 32);
            bf16x8 b1 = *reinterpret_cast<const bf16x8*>(B1 + sub * BK + st * 32);
            acc0 = __builtin_amdgcn_mfma_f32_16x16x32_bf16(af, b0, acc0, 0, 0, 0);
            acc1 = __builtin_amdgcn_mfma_f32_16x16x32_bf16(af, b1, acc1, 0, 0, 0);
        }
    }

    // D layout (16x16x32): col = lane&15, row = (lane>>4)*4 + reg
    const int row0 = rowblk + wave * 16;
    float* sp = Spart + ((size_t)kc * B_ROWS + row0) * NJ;
    const int m0 = (lane >> 4) * 4;
#pragma unroll
    for (int r = 0; r < 4; ++r) {
        sp[(size_t)(m0 + r) * NJ + lrow]      = acc0[r];
        sp[(size_t)(m0 + r) * NJ + 16 + lrow] = acc1[r];
    }
}

// ---------------- Pass 2: sum partials, bias, cos, reduce to q[4] ----------
// grid = 256 blocks * 256 thr = 65536 threads; each thread: 4 (row,j) pairs
extern "C" __global__ __launch_bounds__(256)
void p2_cos_reduce(const float* __restrict__ Spart,
                   const float* __restrict__ bf, const float* __restrict__ bi,
                   const float* __restrict__ bg, const float* __restrict__ bo,
                   float* __restrict__ q)
{
    __shared__ float ql[4];
    if (threadIdx.x < 4) ql[threadIdx.x] = 0.f;
    __syncthreads();

    const int t    = blockIdx.x * 256 + threadIdx.x;  // 0..65535
    const int j    = t & 31;
    const int gate = j >> 3;
    const float* Bp = (gate == 0) ? bf : (gate == 1) ? bi : (gate == 2) ? bg : bo;
    const float bj = Bp[j & 7];

    float accg = 0.f;
#pragma unroll
    for (int i = 0; i < 4; ++i) {
        const int row = (t >> 5) + i * 2048;
        float s = 0.f;
#pragma unroll
        for (int kc = 0; kc < KC; ++kc)
            s += Spart[((size_t)kc * B_ROWS + row) * NJ + j];
        accg += cosf(s + bj);
    }

    accg += __shfl_xor(accg, 1, 64);
    accg += __shfl_xor(accg, 2, 64);
    accg += __shfl_xor(accg, 4, 64);
    if ((threadIdx.x & 7) == 0) atomicAdd(&ql[gate], accg);
    __syncthreads();
    if (threadIdx.x < 4) atomicAdd(&q[threadIdx.x], ql[threadIdx.x]);
}

// ---------------- Pass 3: elementwise LSTM update ----------------
extern "C" __global__ __launch_bounds__(256)
void p3_elementwise(const float* __restrict__ cx, const float* __restrict__ q,
                    float* __restrict__ out)
{
    const float qf = q[0], qi = q[1], qg = q[2], qo = q[3];
    const float f  = 1.f / (1.f + expf(-qf));
    const float ii = 1.f / (1.f + expf(-qi));
    const float g  = tanhf(qg);
    const float o  = 1.f / (1.f + expf(-qo));
    const float ig = ii * g;

    const size_t N  = (size_t)B_ROWS * HIDDEN;
    const size_t N4 = N >> 2;
    const f32x4* cx4 = (const f32x4*)cx;
    f32x4* outh = (f32x4*)out;
    f32x4* outc = (f32x4*)(out + N);

    for (size_t idx = (size_t)blockIdx.x * blockDim.x + threadIdx.x; idx < N4;
         idx += (size_t)gridDim.x * blockDim.x) {
        f32x4 c = __builtin_nontemporal_load(cx4 + idx);  // streaming, no reuse
        f32x4 cn, hn;
        cn.x = fmaf(f, c.x, ig);
        cn.y = fmaf(f, c.y, ig);
        cn.z = fmaf(f, c.z, ig);
        cn.w = fmaf(f, c.w, ig);
        hn.x = o * tanhf(cn.x);
        hn.y = o * tanhf(cn.y);
        hn.z = o * tanhf(cn.z);
        hn.w = o * tanhf(cn.w);
        outc[idx] = cn;
        outh[idx] = hn;
    }
}

// ---------------- launcher ----------------
extern "C" void kernel_launch(void* const* d_in, const int* in_sizes, int n_in,
                              void* d_out, int out_size, void* d_ws, size_t ws_size,
                              hipStream_t stream)
{
    const float* x  = (const float*)d_in[0];
    const float* hx = (const float*)d_in[1];
    const float* cx = (const float*)d_in[2];
    const float* Wf = (const float*)d_in[3];
    const float* bf = (const float*)d_in[4];
    const float* Wi = (const float*)d_in[5];
    const float* bi = (const float*)d_in[6];
    const float* Wg = (const float*)d_in[7];
    const float* bg = (const float*)d_in[8];
    const float* Wo = (const float*)d_in[9];
    const float* bo = (const float*)d_in[10];
    float* out = (float*)d_out;

    // ws layout: Spart [KC][8192][32] f32 (8 MB) | Wb [32][4096] bf16 (256 KB) | q[4]
    float*   Spart = (float*)d_ws;
    __bf16*  Wb    = (__bf16*)(Spart + (size_t)KC * B_ROWS * NJ);
    float*   q     = (float*)(Wb + (size_t)NJ * KDIM);

    w_pack<<<dim3(128), dim3(256), 0, stream>>>(Wf, Wi, Wg, Wo, Wb, q);
    p1_mfma<<<dim3(128 * KC), dim3(256), 0, stream>>>(x, hx, Wb, Spart);
    p2_cos_reduce<<<dim3(256), dim3(256), 0, stream>>>(Spart, bf, bi, bg, bo, q);
    p3_elementwise<<<dim3(2048), dim3(256), 0, stream>>>(cx, q, out);
}